// Round 6
// baseline (290.342 us; speedup 1.0000x reference)
//
#include <hip/hip_runtime.h>

#define N_NODES 50000
#define N_EDGES 800000
#define D 256
#define SCAN_BLOCKS 49   // ceil(50000/1024)

typedef unsigned short bf16_t;
typedef __attribute__((ext_vector_type(8))) short short8;
typedef __attribute__((ext_vector_type(4))) float f32x4;

__device__ inline float b2f(bf16_t u) {
    union { float f; unsigned v; } t; t.v = ((unsigned)u) << 16; return t.f;
}
__device__ inline bf16_t f2b(float f) {
    union { float f; unsigned v; } t; t.f = f;
    unsigned u = t.v;
    return (bf16_t)((u + 0x7FFFu + ((u >> 16) & 1u)) >> 16);   // RNE
}
__device__ inline unsigned cvt_pk_bf16(float lo, float hi) {
    unsigned r;
    asm("v_cvt_pk_bf16_f32 %0, %1, %2" : "=v"(r) : "v"(lo), "v"(hi));
    return r;
}
__device__ inline short8 cvt8(float4 a, float4 b) {
    union { short8 s; unsigned u[4]; } t;
    t.u[0] = cvt_pk_bf16(a.x, a.y);
    t.u[1] = cvt_pk_bf16(a.z, a.w);
    t.u[2] = cvt_pk_bf16(b.x, b.y);
    t.u[3] = cvt_pk_bf16(b.z, b.w);
    return t.s;
}

// ---------------------------------------------------------------------------
// 1. Degree histogram over edge destinations.
// ---------------------------------------------------------------------------
__global__ void deg_kernel(const int* __restrict__ ei, int* __restrict__ deg) {
    int e = blockIdx.x * blockDim.x + threadIdx.x;
    if (e < N_EDGES) {
        int d = ei[N_EDGES + e];
        if ((unsigned)d < (unsigned)N_NODES) atomicAdd(&deg[d], 1);
    }
}

// ---------------------------------------------------------------------------
// 2a. Block-local exclusive scan (wave shuffle based). loc = local exclusive.
// ---------------------------------------------------------------------------
__global__ __launch_bounds__(1024) void scan1_kernel(const int* __restrict__ deg,
                                                     int* __restrict__ loc,
                                                     int* __restrict__ blk_sum) {
    int i = blockIdx.x * 1024 + threadIdx.x;
    int v = (i < N_NODES) ? deg[i] : 0;
    int lane = threadIdx.x & 63;
    int wid  = threadIdx.x >> 6;  // 0..15
    int s = v;
#pragma unroll
    for (int off = 1; off < 64; off <<= 1) {
        int t = __shfl_up(s, off, 64);
        if (lane >= off) s += t;
    }
    __shared__ int wsum[16];
    if (lane == 63) wsum[wid] = s;
    __syncthreads();
    if (threadIdx.x < 16) {
        int ws = wsum[threadIdx.x];
        int t0 = ws;
#pragma unroll
        for (int off = 1; off < 16; off <<= 1) {
            int t = __shfl_up(t0, off, 64);
            if ((int)threadIdx.x >= off) t0 += t;
        }
        wsum[threadIdx.x] = t0 - ws;  // exclusive wave offset
        if (threadIdx.x == 15) blk_sum[blockIdx.x] = t0;
    }
    __syncthreads();
    if (i < N_NODES) loc[i] = wsum[wid] + s - v;
}

// ---------------------------------------------------------------------------
// 2b. Apply block offsets (each block redundantly scans the 49 block sums —
//     kills the separate scan2 launch); emit row_ptr, cursor, dinv.
// ---------------------------------------------------------------------------
__global__ __launch_bounds__(1024) void scan3_kernel(int* __restrict__ loc_cursor,
                                                     const int* __restrict__ blk_sum,
                                                     const int* __restrict__ deg,
                                                     int* __restrict__ row_ptr,
                                                     float* __restrict__ dinv) {
    __shared__ int sh_off, sh_tot;
    if (threadIdx.x < 64) {
        int l = threadIdx.x;
        int v = (l < SCAN_BLOCKS) ? blk_sum[l] : 0;
        int s = v;
#pragma unroll
        for (int off = 1; off < 64; off <<= 1) {
            int t = __shfl_up(s, off, 64);
            if (l >= off) s += t;
        }
        if (l == (int)blockIdx.x)    sh_off = s - v;   // exclusive prefix for this block
        if (l == SCAN_BLOCKS - 1)    sh_tot = s;       // grand total
    }
    __syncthreads();
    int i = blockIdx.x * 1024 + threadIdx.x;
    if (i < N_NODES) {
        int rp = loc_cursor[i] + sh_off;
        row_ptr[i] = rp;
        loc_cursor[i] = rp;  // becomes cursor
        dinv[i] = rsqrtf((float)(deg[i] + 1));
    }
    if (blockIdx.x == SCAN_BLOCKS - 1 && threadIdx.x == 0) row_ptr[N_NODES] = sh_tot;
}

// ---------------------------------------------------------------------------
// 3. Bucket fill: csr_src[pos] = src for each edge, bucketed by dst.
// ---------------------------------------------------------------------------
__global__ void fill_kernel(const int* __restrict__ ei, int* __restrict__ cursor,
                            int* __restrict__ csr_src) {
    int e = blockIdx.x * blockDim.x + threadIdx.x;
    if (e < N_EDGES) {
        int s = ei[e];
        int d = ei[N_EDGES + e];
        if ((unsigned)d < (unsigned)N_NODES) {
            int pos = atomicAdd(&cursor[d], 1);
            csr_src[pos] = s;
        }
    }
}

// ---------------------------------------------------------------------------
// 4. fp32 -> bf16 convert (used only for W: 64 KB bf16 out)
// ---------------------------------------------------------------------------
__global__ void cvt_kernel(const float* __restrict__ in, bf16_t* __restrict__ out, int n4) {
    int i = blockIdx.x * blockDim.x + threadIdx.x;
    if (i >= n4) return;
    float4 v = reinterpret_cast<const float4*>(in)[i];
    ushort4 o;
    o.x = f2b(v.x); o.y = f2b(v.y); o.z = f2b(v.z); o.w = f2b(v.w);
    reinterpret_cast<ushort4*>(out)[i] = o;
}

// ---------------------------------------------------------------------------
// 5. h = x @ W^T, fp32 x (cvt fused) / bf16 W / bf16 out.
//    64 rows x 256 cols per block, 512 thr = 8 waves, each wave 64x32
//    (4x2 fragments of 16x16x32), register double-buffered k-pipeline.
//    A[i][k]: lane l holds row i=l&15, k=(l>>4)*8+b ; B same, col=l&15.
//    D[i][j]: col = l&15, row = (l>>4)*4 + reg        (m89-verified)
// ---------------------------------------------------------------------------
__global__ __launch_bounds__(512) void mfma_gemm_kernel(const float* __restrict__ x,
                                                        const bf16_t* __restrict__ Wb,
                                                        bf16_t* __restrict__ h) {
    const int wid  = threadIdx.x >> 6;   // 0..7 — 32-col group
    const int lane = threadIdx.x & 63;
    const int row0 = blockIdx.x * 64;
    const int col0 = wid * 32;
    const int lr = lane & 15;
    const int lk = (lane >> 4) * 8;

    int r[4];
#pragma unroll
    for (int m = 0; m < 4; m++) {
        int rr = row0 + m * 16 + lr;
        r[m] = (rr < N_NODES) ? rr : (N_NODES - 1);  // clamp; store guarded
    }
    const bf16_t* wp0 = &Wb[(size_t)(col0 + lr) * D + lk];
    const bf16_t* wp1 = &Wb[(size_t)(col0 + 16 + lr) * D + lk];

    f32x4 acc[4][2] = {};
    short8 a0[4], b0[2], a1[4], b1[2];

#define LDFRAG(A, B, K)                                                              \
    {                                                                                \
        _Pragma("unroll")                                                            \
        for (int m = 0; m < 4; m++) {                                                \
            const float4* p = reinterpret_cast<const float4*>(&x[(size_t)r[m] * D + (K) + lk]); \
            A[m] = cvt8(p[0], p[1]);                                                 \
        }                                                                            \
        B[0] = *reinterpret_cast<const short8*>(&wp0[(K)]);                          \
        B[1] = *reinterpret_cast<const short8*>(&wp1[(K)]);                          \
    }
#define DOMFMA(A, B)                                                                 \
    {                                                                                \
        _Pragma("unroll")                                                            \
        for (int m = 0; m < 4; m++) {                                                \
            acc[m][0] = __builtin_amdgcn_mfma_f32_16x16x32_bf16(A[m], B[0], acc[m][0], 0, 0, 0); \
            acc[m][1] = __builtin_amdgcn_mfma_f32_16x16x32_bf16(A[m], B[1], acc[m][1], 0, 0, 0); \
        }                                                                            \
    }

    LDFRAG(a0, b0, 0)
#pragma unroll
    for (int kk = 0; kk < 4; kk++) {
        LDFRAG(a1, b1, kk * 64 + 32)
        DOMFMA(a0, b0)
        if (kk < 3) LDFRAG(a0, b0, kk * 64 + 64)
        DOMFMA(a1, b1)
    }
#undef LDFRAG
#undef DOMFMA

#pragma unroll
    for (int m = 0; m < 4; m++) {
        int rbase = row0 + m * 16 + (lane >> 4) * 4;
#pragma unroll
        for (int j = 0; j < 4; j++) {
            int rr = rbase + j;
            if (rr < N_NODES) {
                h[(size_t)rr * D + col0 + lr]      = f2b(acc[m][0][j]);
                h[(size_t)rr * D + col0 + 16 + lr] = f2b(acc[m][1][j]);
            }
        }
    }
}

// ---------------------------------------------------------------------------
// 6. Gather-reduce, XCD-column-partitioned: blockIdx.x = 32-col chunk, which
//    under round-robin dispatch pins each h column-slice (3.2 MB) into one
//    XCD's L2. 16-lane group per node (4 nodes/wave), 2 cols per lane.
// ---------------------------------------------------------------------------
__global__ __launch_bounds__(256) void gather_kernel(const int* __restrict__ row_ptr,
                                                     const int* __restrict__ csr_src,
                                                     const float* __restrict__ dinv,
                                                     const bf16_t* __restrict__ h,
                                                     const float* __restrict__ x,
                                                     const float* __restrict__ b,
                                                     const float* __restrict__ alpha,
                                                     float* __restrict__ out) {
    const int c0   = blockIdx.x * 32;        // col chunk (0..7) -> XCD
    const int lane = threadIdx.x & 63;
    const int wv   = threadIdx.x >> 6;       // 0..3
    const int grp  = lane >> 4;              // 0..3 — node within wave
    const int ln   = lane & 15;              // col pair within chunk
    const int n = blockIdx.y * 16 + wv * 4 + grp;
    if (n >= N_NODES) return;
    const int col = c0 + ln * 2;

    const int beg = row_ptr[n];
    const int end = row_ptr[n + 1];
    const float dn = dinv[n];
    const bf16_t* hc = h + col;

    float ax = 0.f, ay = 0.f;
    int k = beg;
    for (; k + 3 < end; k += 4) {
        int s0 = csr_src[k], s1 = csr_src[k + 1], s2 = csr_src[k + 2], s3 = csr_src[k + 3];
        float n0 = dinv[s0] * dn, n1 = dinv[s1] * dn, n2 = dinv[s2] * dn, n3 = dinv[s3] * dn;
        unsigned v0 = *reinterpret_cast<const unsigned*>(&hc[(size_t)s0 * D]);
        unsigned v1 = *reinterpret_cast<const unsigned*>(&hc[(size_t)s1 * D]);
        unsigned v2 = *reinterpret_cast<const unsigned*>(&hc[(size_t)s2 * D]);
        unsigned v3 = *reinterpret_cast<const unsigned*>(&hc[(size_t)s3 * D]);
        ax += b2f((bf16_t)v0) * n0 + b2f((bf16_t)v1) * n1
            + b2f((bf16_t)v2) * n2 + b2f((bf16_t)v3) * n3;
        ay += b2f((bf16_t)(v0 >> 16)) * n0 + b2f((bf16_t)(v1 >> 16)) * n1
            + b2f((bf16_t)(v2 >> 16)) * n2 + b2f((bf16_t)(v3 >> 16)) * n3;
    }
    for (; k < end; k++) {
        int s0 = csr_src[k];
        float n0 = dinv[s0] * dn;
        unsigned v0 = *reinterpret_cast<const unsigned*>(&hc[(size_t)s0 * D]);
        ax += b2f((bf16_t)v0) * n0;
        ay += b2f((bf16_t)(v0 >> 16)) * n0;
    }

    float dv2 = dn * dn;
    float a   = alpha[0];
    unsigned hv = *reinterpret_cast<const unsigned*>(&hc[(size_t)n * D]);
    float2 xv = *reinterpret_cast<const float2*>(&x[(size_t)n * D + col]);
    float2 bv = *reinterpret_cast<const float2*>(&b[col]);
    float2 r;
    r.x = a * xv.x + (1.0f - a) * (ax + dv2 * b2f((bf16_t)hv) + bv.x);
    r.y = a * xv.y + (1.0f - a) * (ay + dv2 * b2f((bf16_t)(hv >> 16)) + bv.y);
    *reinterpret_cast<float2*>(&out[(size_t)n * D + col]) = r;
}

// ---------------------------------------------------------------------------
extern "C" void kernel_launch(void* const* d_in, const int* in_sizes, int n_in,
                              void* d_out, int out_size, void* d_ws, size_t ws_size,
                              hipStream_t stream) {
    const float* x     = (const float*)d_in[0];
    const int*   ei    = (const int*)d_in[1];
    const float* W     = (const float*)d_in[2];
    const float* b     = (const float*)d_in[3];
    const float* alpha = (const float*)d_in[4];
    float* out = (float*)d_out;

    char* ws = (char*)d_ws;
    const size_t HB = (size_t)N_NODES * D * 2;  // 25,600,000
    bf16_t* h      = (bf16_t*)ws;
    int*   deg     = (int*)  (ws + HB);                 // 200,000
    int*   row_ptr = (int*)  (ws + HB + 200000);        // 200,016 (N+1, padded)
    int*   cursor  = (int*)  (ws + HB + 400016);        // 200,000 (aliases loc)
    float* dinv    = (float*)(ws + HB + 600016);        // 200,000
    int*   blk_sum = (int*)  (ws + HB + 800016);        // 256
    int*   csr_src = (int*)  (ws + HB + 800528);        // 3,200,000
    bf16_t* Wb     = (bf16_t*)(ws + HB + 4000528);      // 131,072

    (void)hipMemsetAsync(deg, 0, (size_t)N_NODES * 4, stream);

    cvt_kernel<<<(D * D / 4 + 255) / 256, 256, 0, stream>>>(W, Wb, D * D / 4);
    deg_kernel<<<(N_EDGES + 255) / 256, 256, 0, stream>>>(ei, deg);
    scan1_kernel<<<SCAN_BLOCKS, 1024, 0, stream>>>(deg, cursor, blk_sum);
    scan3_kernel<<<SCAN_BLOCKS, 1024, 0, stream>>>(cursor, blk_sum, deg, row_ptr, dinv);
    fill_kernel<<<(N_EDGES + 255) / 256, 256, 0, stream>>>(ei, cursor, csr_src);

    mfma_gemm_kernel<<<(N_NODES + 63) / 64, 512, 0, stream>>>(x, Wb, h);

    gather_kernel<<<dim3(8, (N_NODES + 15) / 16), 256, 0, stream>>>(row_ptr, csr_src, dinv, h, x, b, alpha, out);
}

// Round 7
// 205.495 us; speedup vs baseline: 1.4129x; 1.4129x over previous
//
#include <hip/hip_runtime.h>

#define N_NODES 50000
#define N_EDGES 800000
#define D 256
#define SCAN_BLOCKS 49   // ceil(50000/1024)

typedef unsigned short bf16_t;
typedef __attribute__((ext_vector_type(8))) short short8;
typedef __attribute__((ext_vector_type(4))) float f32x4;

__device__ inline float b2f(bf16_t u) {
    union { float f; unsigned v; } t; t.v = ((unsigned)u) << 16; return t.f;
}
__device__ inline bf16_t f2b(float f) {
    union { float f; unsigned v; } t; t.f = f;
    unsigned u = t.v;
    return (bf16_t)((u + 0x7FFFu + ((u >> 16) & 1u)) >> 16);   // RNE
}
__device__ inline unsigned cvt_pk_bf16(float lo, float hi) {
    unsigned r;
    asm("v_cvt_pk_bf16_f32 %0, %1, %2" : "=v"(r) : "v"(lo), "v"(hi));
    return r;
}
__device__ inline short8 cvt8(float4 a, float4 b) {
    union { short8 s; unsigned u[4]; } t;
    t.u[0] = cvt_pk_bf16(a.x, a.y);
    t.u[1] = cvt_pk_bf16(a.z, a.w);
    t.u[2] = cvt_pk_bf16(b.x, b.y);
    t.u[3] = cvt_pk_bf16(b.z, b.w);
    return t.s;
}
// async global->LDS, 16 bytes per lane; lds base must be wave-uniform
__device__ inline void gload_lds16(const bf16_t* g, bf16_t* l) {
    __builtin_amdgcn_global_load_lds((const __attribute__((address_space(1))) unsigned int*)g,
                                     (__attribute__((address_space(3))) unsigned int*)l, 16, 0, 0);
}

// ---------------------------------------------------------------------------
// 1. Degree histogram over edge destinations.
// ---------------------------------------------------------------------------
__global__ void deg_kernel(const int* __restrict__ ei, int* __restrict__ deg) {
    int e = blockIdx.x * blockDim.x + threadIdx.x;
    if (e < N_EDGES) {
        int d = ei[N_EDGES + e];
        if ((unsigned)d < (unsigned)N_NODES) atomicAdd(&deg[d], 1);
    }
}

// ---------------------------------------------------------------------------
// 2a. Block-local exclusive scan (wave shuffle based). loc = local exclusive.
// ---------------------------------------------------------------------------
__global__ __launch_bounds__(1024) void scan1_kernel(const int* __restrict__ deg,
                                                     int* __restrict__ loc,
                                                     int* __restrict__ blk_sum) {
    int i = blockIdx.x * 1024 + threadIdx.x;
    int v = (i < N_NODES) ? deg[i] : 0;
    int lane = threadIdx.x & 63;
    int wid  = threadIdx.x >> 6;  // 0..15
    int s = v;
#pragma unroll
    for (int off = 1; off < 64; off <<= 1) {
        int t = __shfl_up(s, off, 64);
        if (lane >= off) s += t;
    }
    __shared__ int wsum[16];
    if (lane == 63) wsum[wid] = s;
    __syncthreads();
    if (threadIdx.x < 16) {
        int ws = wsum[threadIdx.x];
        int t0 = ws;
#pragma unroll
        for (int off = 1; off < 16; off <<= 1) {
            int t = __shfl_up(t0, off, 64);
            if ((int)threadIdx.x >= off) t0 += t;
        }
        wsum[threadIdx.x] = t0 - ws;  // exclusive wave offset
        if (threadIdx.x == 15) blk_sum[blockIdx.x] = t0;
    }
    __syncthreads();
    if (i < N_NODES) loc[i] = wsum[wid] + s - v;
}

// ---------------------------------------------------------------------------
// 2b. Apply block offsets (each block redundantly scans the 49 block sums);
//     emit row_ptr, cursor, dinv.
// ---------------------------------------------------------------------------
__global__ __launch_bounds__(1024) void scan3_kernel(int* __restrict__ loc_cursor,
                                                     const int* __restrict__ blk_sum,
                                                     const int* __restrict__ deg,
                                                     int* __restrict__ row_ptr,
                                                     float* __restrict__ dinv) {
    __shared__ int sh_off, sh_tot;
    if (threadIdx.x < 64) {
        int l = threadIdx.x;
        int v = (l < SCAN_BLOCKS) ? blk_sum[l] : 0;
        int s = v;
#pragma unroll
        for (int off = 1; off < 64; off <<= 1) {
            int t = __shfl_up(s, off, 64);
            if (l >= off) s += t;
        }
        if (l == (int)blockIdx.x)    sh_off = s - v;
        if (l == SCAN_BLOCKS - 1)    sh_tot = s;
    }
    __syncthreads();
    int i = blockIdx.x * 1024 + threadIdx.x;
    if (i < N_NODES) {
        int rp = loc_cursor[i] + sh_off;
        row_ptr[i] = rp;
        loc_cursor[i] = rp;  // becomes cursor
        dinv[i] = rsqrtf((float)(deg[i] + 1));
    }
    if (blockIdx.x == SCAN_BLOCKS - 1 && threadIdx.x == 0) row_ptr[N_NODES] = sh_tot;
}

// ---------------------------------------------------------------------------
// 3. Bucket fill: csr_src[pos] = src for each edge, bucketed by dst.
// ---------------------------------------------------------------------------
__global__ void fill_kernel(const int* __restrict__ ei, int* __restrict__ cursor,
                            int* __restrict__ csr_src) {
    int e = blockIdx.x * blockDim.x + threadIdx.x;
    if (e < N_EDGES) {
        int s = ei[e];
        int d = ei[N_EDGES + e];
        if ((unsigned)d < (unsigned)N_NODES) {
            int pos = atomicAdd(&cursor[d], 1);
            csr_src[pos] = s;
        }
    }
}

// ---------------------------------------------------------------------------
// 4. fp32 -> bf16 convert (used only for W: 128 KB bf16 out)
// ---------------------------------------------------------------------------
__global__ void cvt_kernel(const float* __restrict__ in, bf16_t* __restrict__ out, int n4) {
    int i = blockIdx.x * blockDim.x + threadIdx.x;
    if (i >= n4) return;
    float4 v = reinterpret_cast<const float4*>(in)[i];
    ushort4 o;
    o.x = f2b(v.x); o.y = f2b(v.y); o.z = f2b(v.z); o.w = f2b(v.w);
    reinterpret_cast<ushort4*>(out)[i] = o;
}

// ---------------------------------------------------------------------------
// 5. h = x @ W^T — m97-style LDS-staged MFMA GEMM.
//    128x128 tile, BK=32, 256 thr = 4 waves (2x2), each wave 64x64 = 4x4
//    frags of 16x16x32. A staged via registers (fp32 load + fused cvt),
//    B staged via global_load_lds(16B) from pre-converted bf16 W.
//    LDS [128][32] bf16: frag read bank-quad = (row*4+chunk)%8 -> all 8
//    quads x 8 lanes = structural optimum, no swizzle needed.
//    D[i][j]: col = l&15, row = (l>>4)*4 + reg        (m89-verified)
// ---------------------------------------------------------------------------
__global__ __launch_bounds__(256) void mfma_gemm_kernel(const float* __restrict__ x,
                                                        const bf16_t* __restrict__ Wb,
                                                        bf16_t* __restrict__ h) {
    __shared__ __align__(16) bf16_t As[128 * 32];
    __shared__ __align__(16) bf16_t Bs[128 * 32];

    const int tid  = threadIdx.x;
    const int wid  = tid >> 6;   // 0..3
    const int lane = tid & 63;
    const int wr = wid >> 1;     // 0..1
    const int wc = wid & 1;      // 0..1
    const int row0 = blockIdx.x * 128;
    const int col0 = blockIdx.y * 128;
    const int lr = lane & 15;
    const int lk = (lane >> 4) * 8;

    // A staging map: thread t -> row=t>>1 (0..127), half=t&1 (k 0..15 / 16..31)
    const int srow  = tid >> 1;
    const int shalf = tid & 1;
    int sr = row0 + srow;
    if (sr >= N_NODES) sr = N_NODES - 1;   // clamp; stores guarded
    const float* agp = &x[(size_t)sr * D + shalf * 16];
    bf16_t* alp = &As[srow * 32 + shalf * 16];

    f32x4 acc[4][4] = {};

    for (int k0 = 0; k0 < D; k0 += 32) {
        // --- stage B: 2 x global_load_lds (fire-and-forget) ---
#pragma unroll
        for (int j = 0; j < 2; j++) {
            int t = j * 256 + tid;
            const bf16_t* g = &Wb[(size_t)(col0 + (t >> 2)) * D + k0 + (t & 3) * 8];
            gload_lds16(g, &Bs[j * 2048 + wid * 512]);   // wave-uniform base
        }
        // --- stage A: fp32 loads + in-reg cvt + LDS write ---
        {
            const float4* p = reinterpret_cast<const float4*>(&agp[k0]);
            float4 v0 = p[0], v1 = p[1], v2 = p[2], v3 = p[3];
            *reinterpret_cast<short8*>(alp)     = cvt8(v0, v1);
            *reinterpret_cast<short8*>(alp + 8) = cvt8(v2, v3);
        }
        __syncthreads();   // drains vmcnt (gload_lds) + lgkmcnt (ds_write)

        // --- frags + 16 MFMA ---
        short8 a[4], b[4];
#pragma unroll
        for (int m = 0; m < 4; m++)
            a[m] = *reinterpret_cast<const short8*>(&As[(wr * 64 + m * 16 + lr) * 32 + lk]);
#pragma unroll
        for (int n = 0; n < 4; n++)
            b[n] = *reinterpret_cast<const short8*>(&Bs[(wc * 64 + n * 16 + lr) * 32 + lk]);
#pragma unroll
        for (int m = 0; m < 4; m++)
#pragma unroll
            for (int n = 0; n < 4; n++)
                acc[m][n] = __builtin_amdgcn_mfma_f32_16x16x32_bf16(a[m], b[n], acc[m][n], 0, 0, 0);
        __syncthreads();
    }

#pragma unroll
    for (int m = 0; m < 4; m++) {
        int rbase = row0 + wr * 64 + m * 16 + (lane >> 4) * 4;
#pragma unroll
        for (int j = 0; j < 4; j++) {
            int rr = rbase + j;
            if (rr < N_NODES) {
#pragma unroll
                for (int n = 0; n < 4; n++)
                    h[(size_t)rr * D + col0 + wc * 64 + n * 16 + lr] = f2b(acc[m][n][j]);
            }
        }
    }
}

// ---------------------------------------------------------------------------
// 6. Gather-reduce + self-loop + bias + alpha blend. One wave per dst node.
//    h is bf16; lane owns 4 columns (8B loads). Unroll-4 for MLP.
// ---------------------------------------------------------------------------
__global__ __launch_bounds__(256) void gather_kernel(const int* __restrict__ row_ptr,
                                                     const int* __restrict__ csr_src,
                                                     const float* __restrict__ dinv,
                                                     const bf16_t* __restrict__ h,
                                                     const float* __restrict__ x,
                                                     const float* __restrict__ b,
                                                     const float* __restrict__ alpha,
                                                     float* __restrict__ out) {
    int n    = blockIdx.x * 4 + (threadIdx.x >> 6);
    int lane = threadIdx.x & 63;
    if (n >= N_NODES) return;

    const int beg = row_ptr[n];
    const int end = row_ptr[n + 1];
    const float dn = dinv[n];
    const bf16_t* hl = h + (size_t)lane * 4;

    float ax = 0.f, ay = 0.f, az = 0.f, aw = 0.f;
    int k = beg;
    for (; k + 3 < end; k += 4) {
        int s0 = csr_src[k];
        int s1 = csr_src[k + 1];
        int s2 = csr_src[k + 2];
        int s3 = csr_src[k + 3];
        float n0 = dinv[s0] * dn;
        float n1 = dinv[s1] * dn;
        float n2 = dinv[s2] * dn;
        float n3 = dinv[s3] * dn;
        ushort4 h0 = *reinterpret_cast<const ushort4*>(&hl[(size_t)s0 * D]);
        ushort4 h1 = *reinterpret_cast<const ushort4*>(&hl[(size_t)s1 * D]);
        ushort4 h2 = *reinterpret_cast<const ushort4*>(&hl[(size_t)s2 * D]);
        ushort4 h3 = *reinterpret_cast<const ushort4*>(&hl[(size_t)s3 * D]);
        ax += b2f(h0.x) * n0 + b2f(h1.x) * n1 + b2f(h2.x) * n2 + b2f(h3.x) * n3;
        ay += b2f(h0.y) * n0 + b2f(h1.y) * n1 + b2f(h2.y) * n2 + b2f(h3.y) * n3;
        az += b2f(h0.z) * n0 + b2f(h1.z) * n1 + b2f(h2.z) * n2 + b2f(h3.z) * n3;
        aw += b2f(h0.w) * n0 + b2f(h1.w) * n1 + b2f(h2.w) * n2 + b2f(h3.w) * n3;
    }
    for (; k < end; k++) {
        int s0 = csr_src[k];
        float n0 = dinv[s0] * dn;
        ushort4 h0 = *reinterpret_cast<const ushort4*>(&hl[(size_t)s0 * D]);
        ax += b2f(h0.x) * n0;
        ay += b2f(h0.y) * n0;
        az += b2f(h0.z) * n0;
        aw += b2f(h0.w) * n0;
    }

    float dv2 = dn * dn;
    float a   = alpha[0];
    ushort4 hv = *reinterpret_cast<const ushort4*>(&hl[(size_t)n * D]);
    float4  xv = *reinterpret_cast<const float4*>(&x[(size_t)n * D + lane * 4]);
    float4  bv = *reinterpret_cast<const float4*>(&b[lane * 4]);
    float4 r;
    r.x = a * xv.x + (1.0f - a) * (ax + dv2 * b2f(hv.x) + bv.x);
    r.y = a * xv.y + (1.0f - a) * (ay + dv2 * b2f(hv.y) + bv.y);
    r.z = a * xv.z + (1.0f - a) * (az + dv2 * b2f(hv.z) + bv.z);
    r.w = a * xv.w + (1.0f - a) * (aw + dv2 * b2f(hv.w) + bv.w);
    *reinterpret_cast<float4*>(&out[(size_t)n * D + lane * 4]) = r;
}

// ---------------------------------------------------------------------------
extern "C" void kernel_launch(void* const* d_in, const int* in_sizes, int n_in,
                              void* d_out, int out_size, void* d_ws, size_t ws_size,
                              hipStream_t stream) {
    const float* x     = (const float*)d_in[0];
    const int*   ei    = (const int*)d_in[1];
    const float* W     = (const float*)d_in[2];
    const float* b     = (const float*)d_in[3];
    const float* alpha = (const float*)d_in[4];
    float* out = (float*)d_out;

    char* ws = (char*)d_ws;
    const size_t HB = (size_t)N_NODES * D * 2;  // 25,600,000
    bf16_t* h      = (bf16_t*)ws;
    int*   deg     = (int*)  (ws + HB);                 // 200,000
    int*   row_ptr = (int*)  (ws + HB + 200000);        // 200,016 (N+1, padded)
    int*   cursor  = (int*)  (ws + HB + 400016);        // 200,000 (aliases loc)
    float* dinv    = (float*)(ws + HB + 600016);        // 200,000
    int*   blk_sum = (int*)  (ws + HB + 800016);        // 512
    int*   csr_src = (int*)  (ws + HB + 800528);        // 3,200,000
    bf16_t* Wb     = (bf16_t*)(ws + HB + 4000528);      // 131,072

    (void)hipMemsetAsync(deg, 0, (size_t)N_NODES * 4, stream);

    cvt_kernel<<<(D * D / 4 + 255) / 256, 256, 0, stream>>>(W, Wb, D * D / 4);
    deg_kernel<<<(N_EDGES + 255) / 256, 256, 0, stream>>>(ei, deg);
    scan1_kernel<<<SCAN_BLOCKS, 1024, 0, stream>>>(deg, cursor, blk_sum);
    scan3_kernel<<<SCAN_BLOCKS, 1024, 0, stream>>>(cursor, blk_sum, deg, row_ptr, dinv);
    fill_kernel<<<(N_EDGES + 255) / 256, 256, 0, stream>>>(ei, cursor, csr_src);

    mfma_gemm_kernel<<<dim3((N_NODES + 127) / 128, 2), 256, 0, stream>>>(x, Wb, h);

    gather_kernel<<<(N_NODES + 3) / 4, 256, 0, stream>>>(row_ptr, csr_src, dinv, h, x, b, alpha, out);
}

// Round 8
// 184.576 us; speedup vs baseline: 1.5730x; 1.1133x over previous
//
#include <hip/hip_runtime.h>

#define N_NODES 50000
#define N_EDGES 800000
#define D 256
#define SCAN_BLOCKS 49    // ceil(50000/1024)
#define GEMM_BLOCKS 782   // 391 tile-rows x 2 col-halves
#define DEG_BLOCKS 3125   // ceil(800000/256)

typedef unsigned short bf16_t;
typedef __attribute__((ext_vector_type(8))) short short8;
typedef __attribute__((ext_vector_type(4))) float f32x4;

__device__ inline float b2f(bf16_t u) {
    union { float f; unsigned v; } t; t.v = ((unsigned)u) << 16; return t.f;
}
__device__ inline bf16_t f2b(float f) {
    union { float f; unsigned v; } t; t.f = f;
    unsigned u = t.v;
    return (bf16_t)((u + 0x7FFFu + ((u >> 16) & 1u)) >> 16);   // RNE
}
__device__ inline unsigned cvt_pk_bf16(float lo, float hi) {
    unsigned r;
    asm("v_cvt_pk_bf16_f32 %0, %1, %2" : "=v"(r) : "v"(lo), "v"(hi));
    return r;
}
__device__ inline short8 cvt8(float4 a, float4 b) {
    union { short8 s; unsigned u[4]; } t;
    t.u[0] = cvt_pk_bf16(a.x, a.y);
    t.u[1] = cvt_pk_bf16(a.z, a.w);
    t.u[2] = cvt_pk_bf16(b.x, b.y);
    t.u[3] = cvt_pk_bf16(b.z, b.w);
    return t.s;
}

// ---------------------------------------------------------------------------
// K1: fused {MFMA GEMM | degree histogram} — independent chains, one dispatch.
//    GEMM part (blocks [0, GEMM_BLOCKS)): h = x @ W^T, 128x128 tile, BK=32,
//    4 waves (2x2), wave 64x64 = 4x4 frags of 16x16x32. Both A (x, fp32) and
//    B (W, fp32 — L2-hot 256 KB) reg-staged with fused cvt_pk RNE to bf16 LDS.
//    LDS [128][32] bf16: frag bank-quad = (row*4+chunk)%8 -> conflict-free.
//    D[i][j]: col = l&15, row = (l>>4)*4 + reg        (m89-verified)
//    DEG part (remaining blocks): atomic histogram over edge dst.
// ---------------------------------------------------------------------------
__global__ __launch_bounds__(256) void k1_kernel(const float* __restrict__ x,
                                                 const float* __restrict__ W,
                                                 bf16_t* __restrict__ h,
                                                 const int* __restrict__ ei,
                                                 int* __restrict__ deg) {
    __shared__ __align__(16) bf16_t As[128 * 32];
    __shared__ __align__(16) bf16_t Bs[128 * 32];

    const int tid = threadIdx.x;

    if (blockIdx.x >= GEMM_BLOCKS) {
        // ---- degree histogram ----
        int e = (blockIdx.x - GEMM_BLOCKS) * 256 + tid;
        if (e < N_EDGES) {
            int d = ei[N_EDGES + e];
            if ((unsigned)d < (unsigned)N_NODES) atomicAdd(&deg[d], 1);
        }
        return;
    }

    // ---- GEMM tile ----
    const int gb   = blockIdx.x;
    const int wid  = tid >> 6;   // 0..3
    const int lane = tid & 63;
    const int wr = wid >> 1;     // 0..1
    const int wc = wid & 1;      // 0..1
    const int row0 = (gb >> 1) * 128;
    const int col0 = (gb & 1) * 128;
    const int lr = lane & 15;
    const int lk = (lane >> 4) * 8;

    // staging maps: thread t -> row/col = t>>1 (0..127), half = t&1 (k 0..15/16..31)
    const int srow  = tid >> 1;
    const int shalf = tid & 1;
    int sr = row0 + srow;
    if (sr >= N_NODES) sr = N_NODES - 1;   // clamp; stores guarded
    const float* agp = &x[(size_t)sr * D + shalf * 16];
    const float* bgp = &W[(size_t)(col0 + srow) * D + shalf * 16];
    bf16_t* alp = &As[srow * 32 + shalf * 16];
    bf16_t* blp = &Bs[srow * 32 + shalf * 16];

    f32x4 acc[4][4] = {};

    for (int k0 = 0; k0 < D; k0 += 32) {
        {
            const float4* p = reinterpret_cast<const float4*>(&agp[k0]);
            const float4* q = reinterpret_cast<const float4*>(&bgp[k0]);
            float4 a0 = p[0], a1 = p[1], a2 = p[2], a3 = p[3];
            float4 w0 = q[0], w1 = q[1], w2 = q[2], w3 = q[3];
            *reinterpret_cast<short8*>(alp)     = cvt8(a0, a1);
            *reinterpret_cast<short8*>(alp + 8) = cvt8(a2, a3);
            *reinterpret_cast<short8*>(blp)     = cvt8(w0, w1);
            *reinterpret_cast<short8*>(blp + 8) = cvt8(w2, w3);
        }
        __syncthreads();

        short8 a[4], b[4];
#pragma unroll
        for (int m = 0; m < 4; m++)
            a[m] = *reinterpret_cast<const short8*>(&As[(wr * 64 + m * 16 + lr) * 32 + lk]);
#pragma unroll
        for (int n = 0; n < 4; n++)
            b[n] = *reinterpret_cast<const short8*>(&Bs[(wc * 64 + n * 16 + lr) * 32 + lk]);
#pragma unroll
        for (int m = 0; m < 4; m++)
#pragma unroll
            for (int n = 0; n < 4; n++)
                acc[m][n] = __builtin_amdgcn_mfma_f32_16x16x32_bf16(a[m], b[n], acc[m][n], 0, 0, 0);
        __syncthreads();
    }

#pragma unroll
    for (int m = 0; m < 4; m++) {
        int rbase = row0 + wr * 64 + m * 16 + (lane >> 4) * 4;
#pragma unroll
        for (int j = 0; j < 4; j++) {
            int rr = rbase + j;
            if (rr < N_NODES) {
#pragma unroll
                for (int n = 0; n < 4; n++)
                    h[(size_t)rr * D + col0 + wc * 64 + n * 16 + lr] = f2b(acc[m][n][j]);
            }
        }
    }
}

// ---------------------------------------------------------------------------
// 2a. Block-local exclusive scan (wave shuffle based). loc = local exclusive.
// ---------------------------------------------------------------------------
__global__ __launch_bounds__(1024) void scan1_kernel(const int* __restrict__ deg,
                                                     int* __restrict__ loc,
                                                     int* __restrict__ blk_sum) {
    int i = blockIdx.x * 1024 + threadIdx.x;
    int v = (i < N_NODES) ? deg[i] : 0;
    int lane = threadIdx.x & 63;
    int wid  = threadIdx.x >> 6;  // 0..15
    int s = v;
#pragma unroll
    for (int off = 1; off < 64; off <<= 1) {
        int t = __shfl_up(s, off, 64);
        if (lane >= off) s += t;
    }
    __shared__ int wsum[16];
    if (lane == 63) wsum[wid] = s;
    __syncthreads();
    if (threadIdx.x < 16) {
        int ws = wsum[threadIdx.x];
        int t0 = ws;
#pragma unroll
        for (int off = 1; off < 16; off <<= 1) {
            int t = __shfl_up(t0, off, 64);
            if ((int)threadIdx.x >= off) t0 += t;
        }
        wsum[threadIdx.x] = t0 - ws;  // exclusive wave offset
        if (threadIdx.x == 15) blk_sum[blockIdx.x] = t0;
    }
    __syncthreads();
    if (i < N_NODES) loc[i] = wsum[wid] + s - v;
}

// ---------------------------------------------------------------------------
// 2b. Apply block offsets (each block redundantly scans the 49 block sums);
//     emit row_ptr, cursor, dinv.
// ---------------------------------------------------------------------------
__global__ __launch_bounds__(1024) void scan3_kernel(int* __restrict__ loc_cursor,
                                                     const int* __restrict__ blk_sum,
                                                     const int* __restrict__ deg,
                                                     int* __restrict__ row_ptr,
                                                     float* __restrict__ dinv) {
    __shared__ int sh_off, sh_tot;
    if (threadIdx.x < 64) {
        int l = threadIdx.x;
        int v = (l < SCAN_BLOCKS) ? blk_sum[l] : 0;
        int s = v;
#pragma unroll
        for (int off = 1; off < 64; off <<= 1) {
            int t = __shfl_up(s, off, 64);
            if (l >= off) s += t;
        }
        if (l == (int)blockIdx.x)    sh_off = s - v;
        if (l == SCAN_BLOCKS - 1)    sh_tot = s;
    }
    __syncthreads();
    int i = blockIdx.x * 1024 + threadIdx.x;
    if (i < N_NODES) {
        int rp = loc_cursor[i] + sh_off;
        row_ptr[i] = rp;
        loc_cursor[i] = rp;  // becomes cursor
        dinv[i] = rsqrtf((float)(deg[i] + 1));
    }
    if (blockIdx.x == SCAN_BLOCKS - 1 && threadIdx.x == 0) row_ptr[N_NODES] = sh_tot;
}

// ---------------------------------------------------------------------------
// 3. Bucket fill: csr_src[pos] = src for each edge, bucketed by dst.
// ---------------------------------------------------------------------------
__global__ void fill_kernel(const int* __restrict__ ei, int* __restrict__ cursor,
                            int* __restrict__ csr_src) {
    int e = blockIdx.x * blockDim.x + threadIdx.x;
    if (e < N_EDGES) {
        int s = ei[e];
        int d = ei[N_EDGES + e];
        if ((unsigned)d < (unsigned)N_NODES) {
            int pos = atomicAdd(&cursor[d], 1);
            csr_src[pos] = s;
        }
    }
}

// ---------------------------------------------------------------------------
// 4. Gather-reduce + self-loop + bias + alpha blend. One wave per dst node.
//    h is bf16; lane owns 4 columns (8B loads). Unroll-8 for MLP.
// ---------------------------------------------------------------------------
__global__ __launch_bounds__(256) void gather_kernel(const int* __restrict__ row_ptr,
                                                     const int* __restrict__ csr_src,
                                                     const float* __restrict__ dinv,
                                                     const bf16_t* __restrict__ h,
                                                     const float* __restrict__ x,
                                                     const float* __restrict__ b,
                                                     const float* __restrict__ alpha,
                                                     float* __restrict__ out) {
    int n    = blockIdx.x * 4 + (threadIdx.x >> 6);
    int lane = threadIdx.x & 63;
    if (n >= N_NODES) return;

    const int beg = row_ptr[n];
    const int end = row_ptr[n + 1];
    const float dn = dinv[n];
    const bf16_t* hl = h + (size_t)lane * 4;

    float ax = 0.f, ay = 0.f, az = 0.f, aw = 0.f;
    int k = beg;
    for (; k + 7 < end; k += 8) {
        int s0 = csr_src[k],     s1 = csr_src[k + 1], s2 = csr_src[k + 2], s3 = csr_src[k + 3];
        int s4 = csr_src[k + 4], s5 = csr_src[k + 5], s6 = csr_src[k + 6], s7 = csr_src[k + 7];
        float n0 = dinv[s0] * dn, n1 = dinv[s1] * dn, n2 = dinv[s2] * dn, n3 = dinv[s3] * dn;
        float n4 = dinv[s4] * dn, n5 = dinv[s5] * dn, n6 = dinv[s6] * dn, n7 = dinv[s7] * dn;
        ushort4 h0 = *reinterpret_cast<const ushort4*>(&hl[(size_t)s0 * D]);
        ushort4 h1 = *reinterpret_cast<const ushort4*>(&hl[(size_t)s1 * D]);
        ushort4 h2 = *reinterpret_cast<const ushort4*>(&hl[(size_t)s2 * D]);
        ushort4 h3 = *reinterpret_cast<const ushort4*>(&hl[(size_t)s3 * D]);
        ushort4 h4 = *reinterpret_cast<const ushort4*>(&hl[(size_t)s4 * D]);
        ushort4 h5 = *reinterpret_cast<const ushort4*>(&hl[(size_t)s5 * D]);
        ushort4 h6 = *reinterpret_cast<const ushort4*>(&hl[(size_t)s6 * D]);
        ushort4 h7 = *reinterpret_cast<const ushort4*>(&hl[(size_t)s7 * D]);
        ax += b2f(h0.x) * n0 + b2f(h1.x) * n1 + b2f(h2.x) * n2 + b2f(h3.x) * n3
            + b2f(h4.x) * n4 + b2f(h5.x) * n5 + b2f(h6.x) * n6 + b2f(h7.x) * n7;
        ay += b2f(h0.y) * n0 + b2f(h1.y) * n1 + b2f(h2.y) * n2 + b2f(h3.y) * n3
            + b2f(h4.y) * n4 + b2f(h5.y) * n5 + b2f(h6.y) * n6 + b2f(h7.y) * n7;
        az += b2f(h0.z) * n0 + b2f(h1.z) * n1 + b2f(h2.z) * n2 + b2f(h3.z) * n3
            + b2f(h4.z) * n4 + b2f(h5.z) * n5 + b2f(h6.z) * n6 + b2f(h7.z) * n7;
        aw += b2f(h0.w) * n0 + b2f(h1.w) * n1 + b2f(h2.w) * n2 + b2f(h3.w) * n3
            + b2f(h4.w) * n4 + b2f(h5.w) * n5 + b2f(h6.w) * n6 + b2f(h7.w) * n7;
    }
    for (; k + 3 < end; k += 4) {
        int s0 = csr_src[k], s1 = csr_src[k + 1], s2 = csr_src[k + 2], s3 = csr_src[k + 3];
        float n0 = dinv[s0] * dn, n1 = dinv[s1] * dn, n2 = dinv[s2] * dn, n3 = dinv[s3] * dn;
        ushort4 h0 = *reinterpret_cast<const ushort4*>(&hl[(size_t)s0 * D]);
        ushort4 h1 = *reinterpret_cast<const ushort4*>(&hl[(size_t)s1 * D]);
        ushort4 h2 = *reinterpret_cast<const ushort4*>(&hl[(size_t)s2 * D]);
        ushort4 h3 = *reinterpret_cast<const ushort4*>(&hl[(size_t)s3 * D]);
        ax += b2f(h0.x) * n0 + b2f(h1.x) * n1 + b2f(h2.x) * n2 + b2f(h3.x) * n3;
        ay += b2f(h0.y) * n0 + b2f(h1.y) * n1 + b2f(h2.y) * n2 + b2f(h3.y) * n3;
        az += b2f(h0.z) * n0 + b2f(h1.z) * n1 + b2f(h2.z) * n2 + b2f(h3.z) * n3;
        aw += b2f(h0.w) * n0 + b2f(h1.w) * n1 + b2f(h2.w) * n2 + b2f(h3.w) * n3;
    }
    for (; k < end; k++) {
        int s0 = csr_src[k];
        float n0 = dinv[s0] * dn;
        ushort4 h0 = *reinterpret_cast<const ushort4*>(&hl[(size_t)s0 * D]);
        ax += b2f(h0.x) * n0;
        ay += b2f(h0.y) * n0;
        az += b2f(h0.z) * n0;
        aw += b2f(h0.w) * n0;
    }

    float dv2 = dn * dn;
    float a   = alpha[0];
    ushort4 hv = *reinterpret_cast<const ushort4*>(&hl[(size_t)n * D]);
    float4  xv = *reinterpret_cast<const float4*>(&x[(size_t)n * D + lane * 4]);
    float4  bv = *reinterpret_cast<const float4*>(&b[lane * 4]);
    float4 r;
    r.x = a * xv.x + (1.0f - a) * (ax + dv2 * b2f(hv.x) + bv.x);
    r.y = a * xv.y + (1.0f - a) * (ay + dv2 * b2f(hv.y) + bv.y);
    r.z = a * xv.z + (1.0f - a) * (az + dv2 * b2f(hv.z) + bv.z);
    r.w = a * xv.w + (1.0f - a) * (aw + dv2 * b2f(hv.w) + bv.w);
    *reinterpret_cast<float4*>(&out[(size_t)n * D + lane * 4]) = r;
}

// ---------------------------------------------------------------------------
extern "C" void kernel_launch(void* const* d_in, const int* in_sizes, int n_in,
                              void* d_out, int out_size, void* d_ws, size_t ws_size,
                              hipStream_t stream) {
    const float* x     = (const float*)d_in[0];
    const int*   ei    = (const int*)d_in[1];
    const float* W     = (const float*)d_in[2];
    const float* b     = (const float*)d_in[3];
    const float* alpha = (const float*)d_in[4];
    float* out = (float*)d_out;

    char* ws = (char*)d_ws;
    const size_t HB = (size_t)N_NODES * D * 2;  // 25,600,000
    bf16_t* h      = (bf16_t*)ws;
    int*   deg     = (int*)  (ws + HB);                 // 200,000
    int*   row_ptr = (int*)  (ws + HB + 200000);        // 200,016 (N+1, padded)
    int*   cursor  = (int*)  (ws + HB + 400016);        // 200,000 (aliases loc)
    float* dinv    = (float*)(ws + HB + 600016);        // 200,000
    int*   blk_sum = (int*)  (ws + HB + 800016);        // 512
    int*   csr_src = (int*)  (ws + HB + 800528);        // 3,200,000

    (void)hipMemsetAsync(deg, 0, (size_t)N_NODES * 4, stream);

    k1_kernel<<<GEMM_BLOCKS + DEG_BLOCKS, 256, 0, stream>>>(x, W, h, ei, deg);
    scan1_kernel<<<SCAN_BLOCKS, 1024, 0, stream>>>(deg, cursor, blk_sum);
    scan3_kernel<<<SCAN_BLOCKS, 1024, 0, stream>>>(cursor, blk_sum, deg, row_ptr, dinv);
    fill_kernel<<<(N_EDGES + 255) / 256, 256, 0, stream>>>(ei, cursor, csr_src);

    gather_kernel<<<(N_NODES + 3) / 4, 256, 0, stream>>>(row_ptr, csr_src, dinv, h, x, b, alpha, out);
}